// Round 1
// 909.350 us; speedup vs baseline: 1.0049x; 1.0049x over previous
//
#include <hip/hip_runtime.h>
#include <stdint.h>

#define NB 32768      // batch
#define HH 1024       // hidden (cell)
#define PP 128        // proj size
#define INW 263       // input width
#define K0P 448       // padded K for layer0 gates (263+128 -> 448)
#define K1P 256       // K for layer1 gates (128+128)
#define G4H 4096      // 4*H

typedef __attribute__((ext_vector_type(8))) short short8;
typedef __attribute__((ext_vector_type(4))) float floatx4;

__device__ __forceinline__ unsigned short f2bf(float x) {
    union { float f; unsigned int u; } v; v.f = x;
    unsigned int r = v.u + 0x7fffu + ((v.u >> 16) & 1u);
    return (unsigned short)(r >> 16);
}
__device__ __forceinline__ float sigm(float x) { return 1.f / (1.f + __expf(-x)); }
__device__ __forceinline__ float tanhfast(float x) { return 2.f / (1.f + __expf(-2.f * x)) - 1.f; }

__device__ __forceinline__ void load_lds16(const void* g, void* l) {
    __builtin_amdgcn_global_load_lds((const __attribute__((address_space(1))) void*)g,
                                     (__attribute__((address_space(3))) void*)l,
                                     16, 0, 0);
}

// ---------------- prep: inputs -> bf16 packed (Xcat0 [N,448], Xcat1 hidden half [N,256]) ------
__global__ void prep_inputs(const float* __restrict__ inp, const float* __restrict__ hl,
                            unsigned short* __restrict__ X0, unsigned short* __restrict__ X1) {
    const int T0 = NB * K0P;
    const int T1 = T0 + NB * PP;
    for (int idx = blockIdx.x * 256 + threadIdx.x; idx < T1; idx += gridDim.x * 256) {
        if (idx < T0) {
            int n = idx / K0P, c = idx - n * K0P;
            float v = 0.f;
            if (c < INW) v = inp[n * INW + c];
            else if (c < INW + PP) v = hl[n * PP + (c - INW)];
            X0[idx] = f2bf(v);
        } else {
            int k = idx - T0;
            int n = k >> 7, c = k & 127;
            X1[n * K1P + PP + c] = f2bf(hl[NB * PP + k]);
        }
    }
}

// ---------------- prep: weights (permute rows so each col-block's 128 B-rows are contiguous) ---
__global__ void prep_weights(const float* __restrict__ Wih0, const float* __restrict__ Whh0,
                             const float* __restrict__ Wih1, const float* __restrict__ Whh1,
                             const float* __restrict__ Whr0, const float* __restrict__ Whr1,
                             const float* __restrict__ bih0, const float* __restrict__ bhh0,
                             const float* __restrict__ bih1, const float* __restrict__ bhh1,
                             unsigned short* __restrict__ Wp0, unsigned short* __restrict__ Wp1,
                             unsigned short* __restrict__ Whr0b, unsigned short* __restrict__ Whr1b,
                             float* __restrict__ b0, float* __restrict__ b1) {
    const int T0 = G4H * K0P;
    const int T1 = T0 + G4H * K1P;
    const int T2 = T1 + PP * HH;
    const int T3 = T2 + PP * HH;
    const int T4 = T3 + G4H;
    const int T5 = T4 + G4H;
    for (int idx = blockIdx.x * 256 + threadIdx.x; idx < T5; idx += gridDim.x * 256) {
        if (idx < T0) {
            int r = idx / K0P, c = idx - r * K0P;
            int cbb = r >> 7, tt = r & 127;
            int src = (tt >> 5) * 1024 + cbb * 32 + (tt & 31);
            float v = 0.f;
            if (c < INW) v = Wih0[src * INW + c];
            else if (c < INW + PP) v = Whh0[src * PP + (c - INW)];
            Wp0[idx] = f2bf(v);
        } else if (idx < T1) {
            int k = idx - T0;
            int r = k >> 8, c = k & 255;
            int cbb = r >> 7, tt = r & 127;
            int src = (tt >> 5) * 1024 + cbb * 32 + (tt & 31);
            float v = (c < PP) ? Wih1[src * PP + c] : Whh1[src * PP + (c - PP)];
            Wp1[k] = f2bf(v);
        } else if (idx < T2) {
            int k = idx - T1; Whr0b[k] = f2bf(Whr0[k]);
        } else if (idx < T3) {
            int k = idx - T2; Whr1b[k] = f2bf(Whr1[k]);
        } else if (idx < T4) {
            int k = idx - T3; b0[k] = bih0[k] + bhh0[k];
        } else {
            int k = idx - T4; b1[k] = bih1[k] + bhh1[k];
        }
    }
}

// ---------------- gates GEMM + fused LSTM cell elementwise -------------------------------------
// Double-buffered 2-phase pipeline: stage(next) -> vmcnt(8) -> barrier -> compute(cur) -> barrier.
// Counted vmcnt keeps the next tile's 8 loads in flight across the barrier (T3/T4).
template<int KPAD>
__global__ __launch_bounds__(256, 2) void gemm_gates_k(
    const unsigned short* __restrict__ A,   // [NB, KPAD] bf16 bits
    const unsigned short* __restrict__ Bp,  // [4096, KPAD] permuted bf16 bits
    const float* __restrict__ bias,         // [4096] i|f|g|o
    const float* __restrict__ c_prev,       // [NB, 1024]
    float* __restrict__ c_out,              // [NB, 1024] (d_out cn slice)
    unsigned short* __restrict__ tmp_out)   // [NB, 1024] bf16 = sigmoid(o)*tanh(c_new)
{
    __shared__ unsigned short As[2 * 128 * 64];   // 2 x 16KB
    __shared__ unsigned short Bs[2 * 128 * 64];   // 2 x 16KB   (total 64KB -> 2 blocks/CU)
    const int t  = threadIdx.x;
    const int w  = t >> 6;
    const int l  = t & 63;
    const int lc = l & 15;
    const int q4 = l >> 4;
    const int cb = blockIdx.x;   // 0..31
    const int mb = blockIdx.y;   // 0..255

    floatx4 acc[2][8];
#pragma unroll
    for (int i = 0; i < 2; ++i)
#pragma unroll
        for (int j = 0; j < 8; ++j) acc[i][j] = (floatx4){0.f, 0.f, 0.f, 0.f};

    // ---- hoist epilogue operands: latency hides under the whole K-loop ----
    float cpv[2][2][4];
    float bv[2][4];
#pragma unroll
    for (int u4 = 0; u4 < 2; ++u4) {
        const int hidx = cb * 32 + u4 * 16 + lc;
#pragma unroll
        for (int j = 0; j < 4; ++j) bv[u4][j] = bias[j * 1024 + hidx];
#pragma unroll
        for (int mi = 0; mi < 2; ++mi)
#pragma unroll
            for (int r = 0; r < 4; ++r)
                cpv[u4][mi][r] =
                    c_prev[(size_t)(mb * 128 + w * 32 + mi * 16 + q4 * 4 + r) * 1024 + hidx];
    }
    asm volatile("" ::: "memory");   // pin preloads before staging (vmcnt bookkeeping stays safe)

    const int arow = t >> 3;                         // 0..31
    const int sw   = ((t & 7) ^ ((t >> 3) & 7)) * 8; // XOR-swizzled k-chunk
    const unsigned short* gA = A  + (size_t)(mb * 128 + arow) * KPAD + sw;
    const unsigned short* gB = Bp + (size_t)(cb * 128 + arow) * KPAD + sw;

    constexpr int NT = KPAD / 64;

    // prologue: stage tile 0 into buffer 0 (8 global_load_lds / thread)
    {
        char* lA = (char*)As + t * 16;
        char* lB = (char*)Bs + t * 16;
#pragma unroll
        for (int i = 0; i < 4; ++i) {
            load_lds16(gA + (size_t)(i * 32) * KPAD, lA + i * 4096);
            load_lds16(gB + (size_t)(i * 32) * KPAD, lB + i * 4096);
        }
    }

#pragma unroll
    for (int ki = 0; ki < NT; ++ki) {
        const int cur = ki & 1;
        if (ki + 1 < NT) {
            const int kt = (ki + 1) * 64;
            char* lA = (char*)As + (cur ^ 1) * 16384 + t * 16;
            char* lB = (char*)Bs + (cur ^ 1) * 16384 + t * 16;
#pragma unroll
            for (int i = 0; i < 4; ++i) {
                load_lds16(gA + (size_t)(i * 32) * KPAD + kt, lA + i * 4096);
                load_lds16(gB + (size_t)(i * 32) * KPAD + kt, lB + i * 4096);
            }
            // wait only for buffer[cur]'s 8 loads; next tile's 8 stay in flight
            asm volatile("s_waitcnt vmcnt(8)" ::: "memory");
        } else {
            asm volatile("s_waitcnt vmcnt(0)" ::: "memory");
        }
        __builtin_amdgcn_s_barrier();
        asm volatile("" ::: "memory");   // keep ds_reads below the barrier

        const short* Asp = (const short*)As + cur * 8192;
        const short* Bsp = (const short*)Bs + cur * 8192;
#pragma unroll
        for (int kc = 0; kc < 2; ++kc) {
            const int kchunk = kc * 4 + q4;
            const int rsw = (kchunk ^ (lc & 7)) * 8;
            short8 a[2];
#pragma unroll
            for (int mi = 0; mi < 2; ++mi)
                a[mi] = *(const short8*)&Asp[(w * 32 + mi * 16 + lc) * 64 + rsw];
#pragma unroll
            for (int ci = 0; ci < 8; ++ci) {
                short8 b = *(const short8*)&Bsp[(ci * 16 + lc) * 64 + rsw];
#pragma unroll
                for (int mi = 0; mi < 2; ++mi)
                    acc[mi][ci] = __builtin_amdgcn_mfma_f32_16x16x32_bf16(a[mi], b, acc[mi][ci], 0, 0, 0);
            }
        }
        if (ki + 1 < NT) {
            asm volatile("" ::: "memory");   // keep ds_reads above the barrier
            __builtin_amdgcn_s_barrier();
            asm volatile("" ::: "memory");   // keep next stage's loads below the barrier
        }
    }

    // fused LSTM cell epilogue
#pragma unroll
    for (int u4 = 0; u4 < 2; ++u4) {
        const int hidx = cb * 32 + u4 * 16 + lc;
        const float bi = bv[u4][0];
        const float bf = bv[u4][1];
        const float bg = bv[u4][2];
        const float bo = bv[u4][3];
#pragma unroll
        for (int mi = 0; mi < 2; ++mi) {
#pragma unroll
            for (int r = 0; r < 4; ++r) {
                const int row = mb * 128 + w * 32 + mi * 16 + q4 * 4 + r;
                const float iv = acc[mi][0 + u4][r] + bi;
                const float fv = acc[mi][2 + u4][r] + bf;
                const float gv = acc[mi][4 + u4][r] + bg;
                const float ov = acc[mi][6 + u4][r] + bo;
                const float cp = cpv[u4][mi][r];
                const float cn = sigm(fv) * cp + sigm(iv) * tanhfast(gv);
                c_out[(size_t)row * 1024 + hidx] = cn;
                tmp_out[(size_t)row * 1024 + hidx] = f2bf(sigm(ov) * tanhfast(cn));
            }
        }
    }
}

// ---------------- projection GEMM: h = tmp @ Whr^T  (K=1024, 128 out cols) ---------------------
// Same 2-phase double-buffered pipeline. grid=256 => 1 block/CU: intra-block overlap is the only
// latency hiding available here.
__global__ __launch_bounds__(256, 2) void gemm_proj_k(
    const unsigned short* __restrict__ A,   // [NB, 1024] bf16 bits
    const unsigned short* __restrict__ B,   // [128, 1024] bf16 bits
    float* __restrict__ hout,               // [NB, 128] (d_out hn slice)
    unsigned short* __restrict__ xc1)       // [NB, 256] cols 0..127 (layer1 input) or null
{
    __shared__ unsigned short As[2 * 128 * 64];
    __shared__ unsigned short Bs[2 * 128 * 64];
    const int t  = threadIdx.x;
    const int w  = t >> 6;
    const int l  = t & 63;
    const int lc = l & 15;
    const int q4 = l >> 4;
    const int mb = blockIdx.x;   // 0..255

    floatx4 acc[2][8];
#pragma unroll
    for (int i = 0; i < 2; ++i)
#pragma unroll
        for (int j = 0; j < 8; ++j) acc[i][j] = (floatx4){0.f, 0.f, 0.f, 0.f};

    const int arow = t >> 3;
    const int sw   = ((t & 7) ^ ((t >> 3) & 7)) * 8;
    const unsigned short* gA = A + (size_t)(mb * 128 + arow) * 1024 + sw;
    const unsigned short* gB = B + (size_t)arow * 1024 + sw;

    constexpr int NT = 1024 / 64;   // 16

    {
        char* lA = (char*)As + t * 16;
        char* lB = (char*)Bs + t * 16;
#pragma unroll
        for (int i = 0; i < 4; ++i) {
            load_lds16(gA + (size_t)(i * 32) * 1024, lA + i * 4096);
            load_lds16(gB + (size_t)(i * 32) * 1024, lB + i * 4096);
        }
    }

#pragma unroll
    for (int ki = 0; ki < NT; ++ki) {
        const int cur = ki & 1;
        if (ki + 1 < NT) {
            const int kt = (ki + 1) * 64;
            char* lA = (char*)As + (cur ^ 1) * 16384 + t * 16;
            char* lB = (char*)Bs + (cur ^ 1) * 16384 + t * 16;
#pragma unroll
            for (int i = 0; i < 4; ++i) {
                load_lds16(gA + (size_t)(i * 32) * 1024 + kt, lA + i * 4096);
                load_lds16(gB + (size_t)(i * 32) * 1024 + kt, lB + i * 4096);
            }
            asm volatile("s_waitcnt vmcnt(8)" ::: "memory");
        } else {
            asm volatile("s_waitcnt vmcnt(0)" ::: "memory");
        }
        __builtin_amdgcn_s_barrier();
        asm volatile("" ::: "memory");

        const short* Asp = (const short*)As + cur * 8192;
        const short* Bsp = (const short*)Bs + cur * 8192;
#pragma unroll
        for (int kc = 0; kc < 2; ++kc) {
            const int kchunk = kc * 4 + q4;
            const int rsw = (kchunk ^ (lc & 7)) * 8;
            short8 a[2];
#pragma unroll
            for (int mi = 0; mi < 2; ++mi)
                a[mi] = *(const short8*)&Asp[(w * 32 + mi * 16 + lc) * 64 + rsw];
#pragma unroll
            for (int ci = 0; ci < 8; ++ci) {
                short8 b = *(const short8*)&Bsp[(ci * 16 + lc) * 64 + rsw];
#pragma unroll
                for (int mi = 0; mi < 2; ++mi)
                    acc[mi][ci] = __builtin_amdgcn_mfma_f32_16x16x32_bf16(a[mi], b, acc[mi][ci], 0, 0, 0);
            }
        }
        if (ki + 1 < NT) {
            asm volatile("" ::: "memory");
            __builtin_amdgcn_s_barrier();
            asm volatile("" ::: "memory");
        }
    }

#pragma unroll
    for (int ci = 0; ci < 8; ++ci) {
        const int col = ci * 16 + lc;
#pragma unroll
        for (int mi = 0; mi < 2; ++mi) {
#pragma unroll
            for (int r = 0; r < 4; ++r) {
                const int row = mb * 128 + w * 32 + mi * 16 + q4 * 4 + r;
                const float v = acc[mi][ci][r];
                hout[(size_t)row * 128 + col] = v;
                if (xc1) xc1[(size_t)row * K1P + col] = f2bf(v);
            }
        }
    }
}

// ---------------- softmax(h1 + prior) over 128 cols --------------------------------------------
__global__ void softmax_k(const float* __restrict__ h1, const int* __restrict__ clp,
                          float* __restrict__ out) {
    const int w = threadIdx.x >> 6, l = threadIdx.x & 63;
    const int row = blockIdx.x * 4 + w;
    const int cl = clp[0];
    float pd = 0.f;
    float d = (float)(64 - cl);
    float pv = -(d * d) * (1.f / 16.f);
    float p0 = (cl < 64 && l < 32) ? pv : 0.f;
    float p1 = (cl > 64 && (l + 64) >= 96) ? pv : 0.f;
    (void)pd;
    float v0 = h1[(size_t)row * 128 + l] + p0;
    float v1 = h1[(size_t)row * 128 + 64 + l] + p1;
    float m = fmaxf(v0, v1);
#pragma unroll
    for (int off = 32; off > 0; off >>= 1) m = fmaxf(m, __shfl_xor(m, off, 64));
    float e0 = __expf(v0 - m), e1 = __expf(v1 - m);
    float s = e0 + e1;
#pragma unroll
    for (int off = 32; off > 0; off >>= 1) s += __shfl_xor(s, off, 64);
    float inv = 1.f / s;
    out[(size_t)row * 128 + l] = e0 * inv;
    out[(size_t)row * 128 + 64 + l] = e1 * inv;
}

extern "C" void kernel_launch(void* const* d_in, const int* in_sizes, int n_in,
                              void* d_out, int out_size, void* d_ws, size_t ws_size,
                              hipStream_t stream) {
    const float* input = (const float*)d_in[0];
    const float* hidden = (const float*)d_in[1];    // c-state [2,N,1024]
    const float* hlstm  = (const float*)d_in[2];    // h-state [2,N,128]
    const float* Wih0 = (const float*)d_in[3];
    const float* Whh0 = (const float*)d_in[4];
    const float* bih0 = (const float*)d_in[5];
    const float* bhh0 = (const float*)d_in[6];
    const float* Whr0 = (const float*)d_in[7];
    const float* Wih1 = (const float*)d_in[8];
    const float* Whh1 = (const float*)d_in[9];
    const float* bih1 = (const float*)d_in[10];
    const float* bhh1 = (const float*)d_in[11];
    const float* Whr1 = (const float*)d_in[12];
    const int* curlen = (const int*)d_in[13];

    float* out = (float*)d_out;                         // [N,128]
    float* cn0 = out + (size_t)NB * PP;                 // [N,1024]
    float* cn1 = cn0 + (size_t)NB * HH;                 // [N,1024]
    float* hn0 = cn1 + (size_t)NB * HH;                 // [N,128]
    float* hn1 = hn0 + (size_t)NB * PP;                 // [N,128]

    char* p = (char*)d_ws;
    unsigned short* X0    = (unsigned short*)p; p += (size_t)NB * K0P * 2;
    unsigned short* X1    = (unsigned short*)p; p += (size_t)NB * K1P * 2;
    unsigned short* Wp0   = (unsigned short*)p; p += (size_t)G4H * K0P * 2;
    unsigned short* Wp1   = (unsigned short*)p; p += (size_t)G4H * K1P * 2;
    unsigned short* Whr0b = (unsigned short*)p; p += (size_t)PP * HH * 2;
    unsigned short* Whr1b = (unsigned short*)p; p += (size_t)PP * HH * 2;
    float* b0 = (float*)p; p += (size_t)G4H * 4;
    float* b1 = (float*)p; p += (size_t)G4H * 4;
    unsigned short* tmp0 = (unsigned short*)p; p += (size_t)NB * HH * 2;
    unsigned short* tmp1 = (unsigned short*)p; p += (size_t)NB * HH * 2;

    prep_inputs<<<8192, 256, 0, stream>>>(input, hlstm, X0, X1);
    prep_weights<<<4096, 256, 0, stream>>>(Wih0, Whh0, Wih1, Whh1, Whr0, Whr1,
                                           bih0, bhh0, bih1, bhh1,
                                           Wp0, Wp1, Whr0b, Whr1b, b0, b1);
    gemm_gates_k<K0P><<<dim3(32, 256), 256, 0, stream>>>(X0, Wp0, b0, hidden, cn0, tmp0);
    gemm_proj_k<<<256, 256, 0, stream>>>(tmp0, Whr0b, hn0, X1);
    gemm_gates_k<K1P><<<dim3(32, 256), 256, 0, stream>>>(X1, Wp1, b1, hidden + (size_t)NB * HH, cn1, tmp1);
    gemm_proj_k<<<256, 256, 0, stream>>>(tmp1, Whr1b, hn1, nullptr);
    softmax_k<<<NB / 4, 256, 0, stream>>>(hn1, curlen, out);
}

// Round 2
// 906.875 us; speedup vs baseline: 1.0076x; 1.0027x over previous
//
#include <hip/hip_runtime.h>
#include <stdint.h>

#define NB 32768      // batch
#define HH 1024       // hidden (cell)
#define PP 128        // proj size
#define INW 263       // input width
#define K0P 448       // padded K for layer0 gates (263+128 -> 448)
#define K1P 256       // K for layer1 gates (128+128)
#define G4H 4096      // 4*H

typedef __attribute__((ext_vector_type(8))) short short8;
typedef __attribute__((ext_vector_type(4))) float floatx4;

__device__ __forceinline__ unsigned short f2bf(float x) {
    union { float f; unsigned int u; } v; v.f = x;
    unsigned int r = v.u + 0x7fffu + ((v.u >> 16) & 1u);
    return (unsigned short)(r >> 16);
}
__device__ __forceinline__ float sigm(float x) { return 1.f / (1.f + __expf(-x)); }
__device__ __forceinline__ float tanhfast(float x) { return 2.f / (1.f + __expf(-2.f * x)) - 1.f; }

__device__ __forceinline__ void load_lds16(const void* g, void* l) {
    __builtin_amdgcn_global_load_lds((const __attribute__((address_space(1))) void*)g,
                                     (__attribute__((address_space(3))) void*)l,
                                     16, 0, 0);
}

// ---------------- prep: inputs -> bf16 packed (div-free: one block = 4 rows) -------------------
__global__ void prep_inputs(const float* __restrict__ inp, const float* __restrict__ hl,
                            unsigned short* __restrict__ X0, unsigned short* __restrict__ X1) {
    const int n0 = blockIdx.x * 4;
#pragma unroll
    for (int rr = 0; rr < 4; ++rr) {
        const int n = n0 + rr;
        for (int c = threadIdx.x; c < K0P; c += 256) {
            float v = 0.f;
            if (c < INW) v = inp[n * INW + c];
            else if (c < INW + PP) v = hl[n * PP + (c - INW)];
            X0[(size_t)n * K0P + c] = f2bf(v);
        }
        if (threadIdx.x < PP) {
            const int c = threadIdx.x;
            X1[(size_t)n * K1P + PP + c] = f2bf(hl[(size_t)NB * PP + n * PP + c]);
        }
    }
}

// ---------------- prep: weights (div-free: one block = one permuted row) -----------------------
// Wperm row index = cb*128 + t,  src_row = (t>>5)*1024 + cb*32 + (t&31)
__global__ void prep_weights(const float* __restrict__ Wih0, const float* __restrict__ Whh0,
                             const float* __restrict__ Wih1, const float* __restrict__ Whh1,
                             const float* __restrict__ Whr0, const float* __restrict__ Whr1,
                             const float* __restrict__ bih0, const float* __restrict__ bhh0,
                             const float* __restrict__ bih1, const float* __restrict__ bhh1,
                             unsigned short* __restrict__ Wp0, unsigned short* __restrict__ Wp1,
                             unsigned short* __restrict__ Whr0b, unsigned short* __restrict__ Whr1b,
                             float* __restrict__ b0, float* __restrict__ b1) {
    const int b = blockIdx.x;                 // 0..4095
    const int cbb = b >> 7, tt = b & 127;
    const int src = (tt >> 5) * 1024 + cbb * 32 + (tt & 31);
    for (int c = threadIdx.x; c < K0P; c += 256) {
        float v = 0.f;
        if (c < INW) v = Wih0[src * INW + c];
        else if (c < INW + PP) v = Whh0[src * PP + (c - INW)];
        Wp0[(size_t)b * K0P + c] = f2bf(v);
    }
    for (int c = threadIdx.x; c < K1P; c += 256) {
        float v = (c < PP) ? Wih1[src * PP + c] : Whh1[src * PP + (c - PP)];
        Wp1[(size_t)b * K1P + c] = f2bf(v);
    }
    if (b < PP) {
        for (int c = threadIdx.x; c < HH; c += 256) {
            Whr0b[b * HH + c] = f2bf(Whr0[b * HH + c]);
            Whr1b[b * HH + c] = f2bf(Whr1[b * HH + c]);
        }
    }
    if (b < 16) {
        const int k = b * 256 + threadIdx.x;
        b0[k] = bih0[k] + bhh0[k];
        b1[k] = bih1[k] + bhh1[k];
    }
}

// ---------------- gates GEMM + fused LSTM cell -------------------------------------------------
// BM=256, BN=128, BK=32, triple-buffered (stage 2 ahead), counted vmcnt(12).
// LDS 72KB/block -> 2 blocks/CU. Wave tile 64x128, acc[4][8] (128 AGPR).
// BK=32 rows are 64B -> chunk swizzle pos = q4 ^ ((lc>>1)&3) applied on BOTH the pre-swizzled
// global staging source and the ds_read (rule: both-sides-or-neither).
template<int KPAD>
__global__ __launch_bounds__(256, 2) void gemm_gates_k(
    const unsigned short* __restrict__ A,   // [NB, KPAD] bf16 bits
    const unsigned short* __restrict__ Bp,  // [4096, KPAD] permuted bf16 bits
    const float* __restrict__ bias,         // [4096] i|f|g|o
    const float* __restrict__ c_prev,       // [NB, 1024]
    float* __restrict__ c_out,              // [NB, 1024]
    unsigned short* __restrict__ tmp_out)   // [NB, 1024] bf16 = sigmoid(o)*tanh(c_new)
{
    __shared__ unsigned short As[3 * 256 * 32];   // 3 x 16 KB
    __shared__ unsigned short Bs[3 * 128 * 32];   // 3 x 8 KB
    const int t  = threadIdx.x;
    const int w  = t >> 6;
    const int l  = t & 63;
    const int lc = l & 15;
    const int q4 = l >> 4;
    const int cb = blockIdx.x;   // 0..31
    const int mb = blockIdx.y;   // 0..127

    floatx4 acc[4][8];
#pragma unroll
    for (int i = 0; i < 4; ++i)
#pragma unroll
        for (int j = 0; j < 8; ++j) acc[i][j] = (floatx4){0.f, 0.f, 0.f, 0.f};

    // staging: thread t owns LDS 16B-slot s = t + i*256; row r = s>>2, pos p = t&3,
    // global chunk j = p ^ ((r>>1)&3) = (t&3) ^ ((t>>3)&3)   (i-independent)
    const int ar = t >> 2;
    const int aj = (t & 3) ^ ((t >> 3) & 3);
    const unsigned short* gA = A  + (size_t)(mb * 256 + ar) * KPAD + aj * 8;
    const unsigned short* gB = Bp + (size_t)(cb * 128 + ar) * KPAD + aj * 8;
    char* lA = (char*)As + t * 16;
    char* lB = (char*)Bs + t * 16;

#define GSTAGE(buf, kte) do {                                                       \
    _Pragma("unroll") for (int i_ = 0; i_ < 4; ++i_)                                \
        load_lds16(gA + (size_t)(i_ * 64) * KPAD + (kte), lA + (buf) * 16384 + i_ * 4096); \
    _Pragma("unroll") for (int i_ = 0; i_ < 2; ++i_)                                \
        load_lds16(gB + (size_t)(i_ * 64) * KPAD + (kte), lB + (buf) * 8192 + i_ * 4096);  \
} while (0)

    constexpr int NT = KPAD / 32;

    GSTAGE(0, 0);
    GSTAGE(1, 32);
    GSTAGE(2, 64);

    float cpv[4][2][4];
    float bv[2][4];

#pragma unroll
    for (int ki = 0; ki < NT; ++ki) {
        if (ki < NT - 2)       asm volatile("s_waitcnt vmcnt(12)" ::: "memory");
        else if (ki == NT - 2) asm volatile("s_waitcnt vmcnt(6)" ::: "memory");
        else                   asm volatile("s_waitcnt vmcnt(0)" ::: "memory");

        if (ki == NT - 2) {
            // epilogue operands: one K-step of latency hiding, short VGPR live range
#pragma unroll
            for (int u4 = 0; u4 < 2; ++u4) {
                const int hidx = cb * 32 + u4 * 16 + lc;
#pragma unroll
                for (int j = 0; j < 4; ++j) bv[u4][j] = bias[j * 1024 + hidx];
#pragma unroll
                for (int mi = 0; mi < 4; ++mi)
#pragma unroll
                    for (int r = 0; r < 4; ++r)
                        cpv[mi][u4][r] =
                            c_prev[(size_t)(mb * 256 + w * 64 + mi * 16 + q4 * 4 + r) * 1024 + hidx];
            }
        }

        __builtin_amdgcn_s_barrier();
        asm volatile("" ::: "memory");

        const short* Asp = (const short*)As + (ki % 3) * 8192;
        const short* Bsp = (const short*)Bs + (ki % 3) * 4096;
        const int pos8 = (q4 ^ ((lc >> 1) & 3)) * 8;
        short8 a[4];
#pragma unroll
        for (int mi = 0; mi < 4; ++mi)
            a[mi] = *(const short8*)&Asp[(w * 64 + mi * 16 + lc) * 32 + pos8];
#pragma unroll
        for (int ci = 0; ci < 8; ++ci) {
            short8 b = *(const short8*)&Bsp[(ci * 16 + lc) * 32 + pos8];
#pragma unroll
            for (int mi = 0; mi < 4; ++mi)
                acc[mi][ci] = __builtin_amdgcn_mfma_f32_16x16x32_bf16(a[mi], b, acc[mi][ci], 0, 0, 0);
        }

        if (ki + 3 < NT) {
            asm volatile("" ::: "memory");
            __builtin_amdgcn_s_barrier();   // all waves done reading buf (ki%3) -> safe to restage
            GSTAGE(ki % 3, (ki + 3) * 32);
        }
    }
#undef GSTAGE

    // fused LSTM cell epilogue
#pragma unroll
    for (int u4 = 0; u4 < 2; ++u4) {
        const int hidx = cb * 32 + u4 * 16 + lc;
        const float bi = bv[u4][0];
        const float bf = bv[u4][1];
        const float bg = bv[u4][2];
        const float bo = bv[u4][3];
#pragma unroll
        for (int mi = 0; mi < 4; ++mi) {
#pragma unroll
            for (int r = 0; r < 4; ++r) {
                const int row = mb * 256 + w * 64 + mi * 16 + q4 * 4 + r;
                const float iv = acc[mi][0 + u4][r] + bi;
                const float fv = acc[mi][2 + u4][r] + bf;
                const float gv = acc[mi][4 + u4][r] + bg;
                const float ov = acc[mi][6 + u4][r] + bo;
                const float cp = cpv[mi][u4][r];
                const float cn = sigm(fv) * cp + sigm(iv) * tanhfast(gv);
                c_out[(size_t)row * 1024 + hidx] = cn;
                tmp_out[(size_t)row * 1024 + hidx] = f2bf(sigm(ov) * tanhfast(cn));
            }
        }
    }
}

// ---------------- projection GEMM: h = tmp @ Whr^T  (K=1024, 128 out cols) ---------------------
// BM=64 -> grid 512 -> 2 independent block pipelines per CU. Triple-buffered BK=32, vmcnt(6).
__global__ __launch_bounds__(256, 2) void gemm_proj_k(
    const unsigned short* __restrict__ A,   // [NB, 1024] bf16 bits
    const unsigned short* __restrict__ B,   // [128, 1024] bf16 bits
    float* __restrict__ hout,               // [NB, 128]
    unsigned short* __restrict__ xc1)       // [NB, 256] cols 0..127 or null
{
    __shared__ unsigned short As[3 * 64 * 32];    // 3 x 4 KB
    __shared__ unsigned short Bs[3 * 128 * 32];   // 3 x 8 KB
    const int t  = threadIdx.x;
    const int w  = t >> 6;
    const int l  = t & 63;
    const int lc = l & 15;
    const int q4 = l >> 4;
    const int mb = blockIdx.x;   // 0..511

    floatx4 acc[8];
#pragma unroll
    for (int j = 0; j < 8; ++j) acc[j] = (floatx4){0.f, 0.f, 0.f, 0.f};

    const int ar = t >> 2;
    const int aj = (t & 3) ^ ((t >> 3) & 3);
    const unsigned short* gA = A + (size_t)(mb * 64 + ar) * 1024 + aj * 8;
    const unsigned short* gB = B + (size_t)ar * 1024 + aj * 8;
    char* lA = (char*)As + t * 16;
    char* lB = (char*)Bs + t * 16;

#define PSTAGE(buf, kte) do {                                                      \
    load_lds16(gA + (kte), lA + (buf) * 4096);                                     \
    _Pragma("unroll") for (int i_ = 0; i_ < 2; ++i_)                               \
        load_lds16(gB + (size_t)(i_ * 64) * 1024 + (kte), lB + (buf) * 8192 + i_ * 4096); \
} while (0)

    constexpr int NT = 32;

    PSTAGE(0, 0);
    PSTAGE(1, 32);
    PSTAGE(2, 64);

#pragma unroll
    for (int ki = 0; ki < NT; ++ki) {
        if (ki < NT - 2)       asm volatile("s_waitcnt vmcnt(6)" ::: "memory");
        else if (ki == NT - 2) asm volatile("s_waitcnt vmcnt(3)" ::: "memory");
        else                   asm volatile("s_waitcnt vmcnt(0)" ::: "memory");
        __builtin_amdgcn_s_barrier();
        asm volatile("" ::: "memory");

        const short* Asp = (const short*)As + (ki % 3) * 2048;
        const short* Bsp = (const short*)Bs + (ki % 3) * 4096;
        const int pos8 = (q4 ^ ((lc >> 1) & 3)) * 8;
        short8 a = *(const short8*)&Asp[(w * 16 + lc) * 32 + pos8];
#pragma unroll
        for (int ci = 0; ci < 8; ++ci) {
            short8 b = *(const short8*)&Bsp[(ci * 16 + lc) * 32 + pos8];
            acc[ci] = __builtin_amdgcn_mfma_f32_16x16x32_bf16(a, b, acc[ci], 0, 0, 0);
        }

        if (ki + 3 < NT) {
            asm volatile("" ::: "memory");
            __builtin_amdgcn_s_barrier();
            PSTAGE(ki % 3, (ki + 3) * 32);
        }
    }
#undef PSTAGE

#pragma unroll
    for (int ci = 0; ci < 8; ++ci) {
        const int col = ci * 16 + lc;
#pragma unroll
        for (int r = 0; r < 4; ++r) {
            const int row = mb * 64 + w * 16 + q4 * 4 + r;
            const float v = acc[ci][r];
            hout[(size_t)row * 128 + col] = v;
            if (xc1) xc1[(size_t)row * K1P + col] = f2bf(v);
        }
    }
}

// ---------------- softmax(h1 + prior) over 128 cols --------------------------------------------
__global__ void softmax_k(const float* __restrict__ h1, const int* __restrict__ clp,
                          float* __restrict__ out) {
    const int w = threadIdx.x >> 6, l = threadIdx.x & 63;
    const int row = blockIdx.x * 4 + w;
    const int cl = clp[0];
    float d = (float)(64 - cl);
    float pv = -(d * d) * (1.f / 16.f);
    float p0 = (cl < 64 && l < 32) ? pv : 0.f;
    float p1 = (cl > 64 && (l + 64) >= 96) ? pv : 0.f;
    float v0 = h1[(size_t)row * 128 + l] + p0;
    float v1 = h1[(size_t)row * 128 + 64 + l] + p1;
    float m = fmaxf(v0, v1);
#pragma unroll
    for (int off = 32; off > 0; off >>= 1) m = fmaxf(m, __shfl_xor(m, off, 64));
    float e0 = __expf(v0 - m), e1 = __expf(v1 - m);
    float s = e0 + e1;
#pragma unroll
    for (int off = 32; off > 0; off >>= 1) s += __shfl_xor(s, off, 64);
    float inv = 1.f / s;
    out[(size_t)row * 128 + l] = e0 * inv;
    out[(size_t)row * 128 + 64 + l] = e1 * inv;
}

extern "C" void kernel_launch(void* const* d_in, const int* in_sizes, int n_in,
                              void* d_out, int out_size, void* d_ws, size_t ws_size,
                              hipStream_t stream) {
    const float* input = (const float*)d_in[0];
    const float* hidden = (const float*)d_in[1];    // c-state [2,N,1024]
    const float* hlstm  = (const float*)d_in[2];    // h-state [2,N,128]
    const float* Wih0 = (const float*)d_in[3];
    const float* Whh0 = (const float*)d_in[4];
    const float* bih0 = (const float*)d_in[5];
    const float* bhh0 = (const float*)d_in[6];
    const float* Whr0 = (const float*)d_in[7];
    const float* Wih1 = (const float*)d_in[8];
    const float* Whh1 = (const float*)d_in[9];
    const float* bih1 = (const float*)d_in[10];
    const float* bhh1 = (const float*)d_in[11];
    const float* Whr1 = (const float*)d_in[12];
    const int* curlen = (const int*)d_in[13];

    float* out = (float*)d_out;                         // [N,128]
    float* cn0 = out + (size_t)NB * PP;                 // [N,1024]
    float* cn1 = cn0 + (size_t)NB * HH;                 // [N,1024]
    float* hn0 = cn1 + (size_t)NB * HH;                 // [N,128]
    float* hn1 = hn0 + (size_t)NB * PP;                 // [N,128]

    char* p = (char*)d_ws;
    unsigned short* X0    = (unsigned short*)p; p += (size_t)NB * K0P * 2;
    unsigned short* X1    = (unsigned short*)p; p += (size_t)NB * K1P * 2;
    unsigned short* Wp0   = (unsigned short*)p; p += (size_t)G4H * K0P * 2;
    unsigned short* Wp1   = (unsigned short*)p; p += (size_t)G4H * K1P * 2;
    unsigned short* Whr0b = (unsigned short*)p; p += (size_t)PP * HH * 2;
    unsigned short* Whr1b = (unsigned short*)p; p += (size_t)PP * HH * 2;
    float* b0 = (float*)p; p += (size_t)G4H * 4;
    float* b1 = (float*)p; p += (size_t)G4H * 4;
    unsigned short* tmp0 = (unsigned short*)p; p += (size_t)NB * HH * 2;
    unsigned short* tmp1 = (unsigned short*)p; p += (size_t)NB * HH * 2;

    prep_inputs<<<NB / 4, 256, 0, stream>>>(input, hlstm, X0, X1);
    prep_weights<<<G4H, 256, 0, stream>>>(Wih0, Whh0, Wih1, Whh1, Whr0, Whr1,
                                          bih0, bhh0, bih1, bhh1,
                                          Wp0, Wp1, Whr0b, Whr1b, b0, b1);
    gemm_gates_k<K0P><<<dim3(32, 128), 256, 0, stream>>>(X0, Wp0, b0, hidden, cn0, tmp0);
    gemm_proj_k<<<512, 256, 0, stream>>>(tmp0, Whr0b, hn0, X1);
    gemm_gates_k<K1P><<<dim3(32, 128), 256, 0, stream>>>(X1, Wp1, b1, hidden + (size_t)NB * HH, cn1, tmp1);
    gemm_proj_k<<<512, 256, 0, stream>>>(tmp1, Whr1b, hn1, nullptr);
    softmax_k<<<NB / 4, 256, 0, stream>>>(hn1, curlen, out);
}